// Round 1
// baseline (782.353 us; speedup 1.0000x reference)
//
#include <hip/hip_runtime.h>
#include <hip/hip_bf16.h>
#include <stdint.h>

#define S_TOK 8192
#define DM    1024
#define FFD   4096
#define NE    8
#define CAP   1280

typedef __attribute__((ext_vector_type(8))) __bf16 bf16x8;
typedef __attribute__((ext_vector_type(8))) unsigned short u16x8;
typedef __attribute__((ext_vector_type(4))) float f32x4;

__device__ __forceinline__ unsigned short f2bf(float f) {
    unsigned u = __float_as_uint(f);
    unsigned r = (u + 0x7FFFu + ((u >> 16) & 1u)) >> 16;   // RNE, inputs finite
    return (unsigned short)r;
}

__device__ __forceinline__ void gload_lds16(const void* g, void* l) {
    __builtin_amdgcn_global_load_lds(
        (const __attribute__((address_space(1))) void*)g,
        (__attribute__((address_space(3))) void*)l, 16, 0, 0);
}

// ---------------- gating: one wave per token ----------------
__global__ __launch_bounds__(256) void gate_kernel(
    const float* __restrict__ x, const float* __restrict__ gw,
    const float* __restrict__ gb, int2* __restrict__ tops, float2* __restrict__ wts)
{
    int wave = threadIdx.x >> 6, lane = threadIdx.x & 63;
    int t = blockIdx.x * 4 + wave;
    float acc[NE] = {0,0,0,0,0,0,0,0};
    const float* xr = x + (size_t)t * DM;
    for (int it = 0; it < DM / 64; ++it) {
        int d = it * 64 + lane;
        float xv = xr[d];
        const float4* g4 = (const float4*)(gw + (size_t)d * NE);
        float4 a = g4[0], b = g4[1];
        acc[0] += xv * a.x; acc[1] += xv * a.y; acc[2] += xv * a.z; acc[3] += xv * a.w;
        acc[4] += xv * b.x; acc[5] += xv * b.y; acc[6] += xv * b.z; acc[7] += xv * b.w;
    }
#pragma unroll
    for (int e = 0; e < NE; ++e)
#pragma unroll
        for (int off = 32; off > 0; off >>= 1)
            acc[e] += __shfl_down(acc[e], off, 64);
    if (lane == 0) {
        float lg[NE];
#pragma unroll
        for (int e = 0; e < NE; ++e) lg[e] = acc[e] + gb[e];
        int e1 = 0; float m1 = lg[0];
#pragma unroll
        for (int e = 1; e < NE; ++e) if (lg[e] > m1) { m1 = lg[e]; e1 = e; }
        int e2 = -1; float m2 = -1e30f;
#pragma unroll
        for (int e = 0; e < NE; ++e) if (e != e1 && lg[e] > m2) { m2 = lg[e]; e2 = e; }
        float p1 = 1.f / (1.f + expf(m2 - m1));
        tops[t] = make_int2(e1, e2);
        wts[t] = make_float2(p1, 1.f - p1);
    }
}

// ---------------- capacity scan: 1 block, wave e scans all tokens ----------------
__global__ __launch_bounds__(512) void route_scan(
    const int2* __restrict__ tops, const float2* __restrict__ wts,
    int* __restrict__ idxl, float* __restrict__ tokw)
{
    int e = threadIdx.x >> 6, lane = threadIdx.x & 63;
    for (int s = lane; s < CAP; s += 64) { idxl[e * CAP + s] = S_TOK; tokw[e * CAP + s] = 0.f; }
    int base = 0;
    for (int ch = 0; ch < S_TOK / 64; ++ch) {
        int t = ch * 64 + lane;
        int2 te = tops[t];
        float2 wv = wts[t];
        bool m1 = (te.x == e), m2 = (te.y == e);
        bool a = m1 || m2;
        unsigned long long bal = __ballot(a);
        int pre = __popcll(bal & ((1ull << lane) - 1ull));
        if (a) {
            int slot = base + pre;
            if (slot < CAP) { idxl[e * CAP + slot] = t; tokw[e * CAP + slot] = m1 ? wv.x : wv.y; }
        }
        base += __popcll(bal);
    }
}

// ---------------- x fp32 -> bf16 (+zero pad row S) ----------------
__global__ __launch_bounds__(256) void cvt_x_kernel(const float* __restrict__ x,
                                                    unsigned short* __restrict__ xp)
{
    if (blockIdx.x == (S_TOK * DM / 8) / 256) {         // pad-row block
        if (threadIdx.x < DM / 8) {
            u16x8 z = {0,0,0,0,0,0,0,0};
            *(u16x8*)(xp + (size_t)S_TOK * DM + threadIdx.x * 8) = z;
        }
        return;
    }
    size_t i = (size_t)blockIdx.x * 256 + threadIdx.x;
    const float4* s = (const float4*)(x + i * 8);
    float4 a = s[0], b = s[1];
    u16x8 o;
    o[0]=f2bf(a.x); o[1]=f2bf(a.y); o[2]=f2bf(a.z); o[3]=f2bf(a.w);
    o[4]=f2bf(b.x); o[5]=f2bf(b.y); o[6]=f2bf(b.z); o[7]=f2bf(b.w);
    *(u16x8*)(xp + i * 8) = o;
}

// ---------------- (K,N) fp32 -> (N,K) bf16 transpose-convert, per expert ----------------
__global__ __launch_bounds__(256) void transpose_cvt(
    const float* __restrict__ src, unsigned short* __restrict__ dst, int K, int N)
{
    __shared__ float tile[64][65];
    size_t ebase = (size_t)blockIdx.z * K * N;
    int k0 = blockIdx.y * 64, n0 = blockIdx.x * 64;
    int t = threadIdx.x;
    int tr = t >> 4, tc = (t & 15) * 4;
#pragma unroll
    for (int rr = 0; rr < 4; ++rr) {
        int k = tr + rr * 16;
        float4 v = *(const float4*)(src + ebase + (size_t)(k0 + k) * N + n0 + tc);
        tile[tc + 0][k] = v.x; tile[tc + 1][k] = v.y; tile[tc + 2][k] = v.z; tile[tc + 3][k] = v.w;
    }
    __syncthreads();
    int nr = t >> 3, kc = (t & 7) * 8;
#pragma unroll
    for (int ww = 0; ww < 2; ++ww) {
        int n = nr + ww * 32;
        u16x8 o;
#pragma unroll
        for (int q = 0; q < 8; ++q) o[q] = f2bf(tile[n][kc + q]);
        *(u16x8*)(dst + ebase + (size_t)(n0 + n) * K + k0 + kc) = o;
    }
}

// ---------------- GEMM1: h[e] = relu(gather(x)[e] @ w1[e] + b1[e])  (bf16 out) ----------------
__global__ __launch_bounds__(256) void moe_gemm1(
    const unsigned short* __restrict__ xpad, const unsigned short* __restrict__ w1t,
    const float* __restrict__ b1, const int* __restrict__ idxl, unsigned short* __restrict__ h)
{
    __shared__ unsigned short As[128 * 64];
    __shared__ unsigned short Bs[128 * 64];
    const int MT = CAP / 128, NT = FFD / 128;                 // 10, 32
    int bid = blockIdx.x;
    int e = bid / (MT * NT); int r = bid % (MT * NT);
    int tm = r / NT, tn = r % NT;
    int t = threadIdx.x, wave = t >> 6, lane = t & 63;

    const unsigned short* asrc[4]; const unsigned short* bsrc[4];
#pragma unroll
    for (int i = 0; i < 4; ++i) {
        int row = (i * 256 + t) >> 3;
        int g = idxl[e * CAP + tm * 128 + row];
        asrc[i] = xpad + (size_t)g * DM + (t & 7) * 8;
        bsrc[i] = w1t + ((size_t)e * FFD + tn * 128 + row) * DM + (t & 7) * 8;
    }
    f32x4 acc[4][4] = {};
    int wr = wave >> 1, wc = wave & 1;
    int a_off = (wr * 64 + (lane & 15)) * 64 + (lane >> 4) * 8;
    int b_off = (wc * 64 + (lane & 15)) * 64 + (lane >> 4) * 8;

    for (int kt = 0; kt < DM / 64; ++kt) {
#pragma unroll
        for (int i = 0; i < 4; ++i) {
            gload_lds16(asrc[i] + kt * 64, As + (i * 4 + wave) * 512);
            gload_lds16(bsrc[i] + kt * 64, Bs + (i * 4 + wave) * 512);
        }
        __syncthreads();
#pragma unroll
        for (int kk = 0; kk < 2; ++kk) {
            bf16x8 af[4], bfr[4];
#pragma unroll
            for (int m = 0; m < 4; ++m) af[m]  = *(const bf16x8*)(As + a_off + m * 1024 + kk * 32);
#pragma unroll
            for (int n = 0; n < 4; ++n) bfr[n] = *(const bf16x8*)(Bs + b_off + n * 1024 + kk * 32);
#pragma unroll
            for (int m = 0; m < 4; ++m)
#pragma unroll
                for (int n = 0; n < 4; ++n)
                    acc[m][n] = __builtin_amdgcn_mfma_f32_16x16x32_bf16(af[m], bfr[n], acc[m][n], 0, 0, 0);
        }
        __syncthreads();
    }
    int col0 = tn * 128 + wc * 64 + (lane & 15);
    int row0 = tm * 128 + wr * 64 + ((lane >> 4) * 4);
    float bv[4];
#pragma unroll
    for (int n = 0; n < 4; ++n) bv[n] = b1[(size_t)e * FFD + col0 + n * 16];
#pragma unroll
    for (int m = 0; m < 4; ++m)
#pragma unroll
        for (int j = 0; j < 4; ++j) {
            int row = row0 + m * 16 + j;
            size_t hb = ((size_t)e * CAP + row) * FFD;
#pragma unroll
            for (int n = 0; n < 4; ++n) {
                float v = acc[m][n][j] + bv[n];
                v = fmaxf(v, 0.f);
                h[hb + col0 + n * 16] = f2bf(v);
            }
        }
}

// ---------------- GEMM2: out += scatter( (h[e] @ w2[e] + b2[e]) * tokw ) ----------------
__global__ __launch_bounds__(256) void moe_gemm2(
    const unsigned short* __restrict__ h, const unsigned short* __restrict__ w2t,
    const float* __restrict__ b2, const int* __restrict__ idxl, const float* __restrict__ tokw,
    float* __restrict__ out)
{
    __shared__ unsigned short As[128 * 64];
    __shared__ unsigned short Bs[128 * 64];
    const int MT = CAP / 128, NT = DM / 128;                  // 10, 8
    int bid = blockIdx.x;
    int e = bid / (MT * NT); int r = bid % (MT * NT);
    int tm = r / NT, tn = r % NT;
    int t = threadIdx.x, wave = t >> 6, lane = t & 63;

    const unsigned short* asrc[4]; const unsigned short* bsrc[4];
#pragma unroll
    for (int i = 0; i < 4; ++i) {
        int row = (i * 256 + t) >> 3;
        asrc[i] = h   + ((size_t)e * CAP + tm * 128 + row) * FFD + (t & 7) * 8;
        bsrc[i] = w2t + ((size_t)e * DM  + tn * 128 + row) * FFD + (t & 7) * 8;
    }
    f32x4 acc[4][4] = {};
    int wr = wave >> 1, wc = wave & 1;
    int a_off = (wr * 64 + (lane & 15)) * 64 + (lane >> 4) * 8;
    int b_off = (wc * 64 + (lane & 15)) * 64 + (lane >> 4) * 8;

    for (int kt = 0; kt < FFD / 64; ++kt) {
#pragma unroll
        for (int i = 0; i < 4; ++i) {
            gload_lds16(asrc[i] + kt * 64, As + (i * 4 + wave) * 512);
            gload_lds16(bsrc[i] + kt * 64, Bs + (i * 4 + wave) * 512);
        }
        __syncthreads();
#pragma unroll
        for (int kk = 0; kk < 2; ++kk) {
            bf16x8 af[4], bfr[4];
#pragma unroll
            for (int m = 0; m < 4; ++m) af[m]  = *(const bf16x8*)(As + a_off + m * 1024 + kk * 32);
#pragma unroll
            for (int n = 0; n < 4; ++n) bfr[n] = *(const bf16x8*)(Bs + b_off + n * 1024 + kk * 32);
#pragma unroll
            for (int m = 0; m < 4; ++m)
#pragma unroll
                for (int n = 0; n < 4; ++n)
                    acc[m][n] = __builtin_amdgcn_mfma_f32_16x16x32_bf16(af[m], bfr[n], acc[m][n], 0, 0, 0);
        }
        __syncthreads();
    }
    int col0 = tn * 128 + wc * 64 + (lane & 15);
    int row0 = tm * 128 + wr * 64 + ((lane >> 4) * 4);
    float bv[4];
#pragma unroll
    for (int n = 0; n < 4; ++n) bv[n] = b2[(size_t)e * DM + col0 + n * 16];
#pragma unroll
    for (int m = 0; m < 4; ++m)
#pragma unroll
        for (int j = 0; j < 4; ++j) {
            int row = row0 + m * 16 + j;
            int tok = idxl[e * CAP + row];
            float w = tokw[e * CAP + row];
            if (w != 0.f) {
                float* orow = out + (size_t)tok * DM;
#pragma unroll
                for (int n = 0; n < 4; ++n)
                    atomicAdd(orow + col0 + n * 16, (acc[m][n][j] + bv[n]) * w);
            }
        }
}

extern "C" void kernel_launch(void* const* d_in, const int* in_sizes, int n_in,
                              void* d_out, int out_size, void* d_ws, size_t ws_size,
                              hipStream_t stream) {
    (void)in_sizes; (void)n_in; (void)ws_size;
    const float* x  = (const float*)d_in[0];
    const float* gw = (const float*)d_in[1];
    const float* gb = (const float*)d_in[2];
    const float* w1 = (const float*)d_in[3];
    const float* b1 = (const float*)d_in[4];
    const float* w2 = (const float*)d_in[5];
    const float* b2 = (const float*)d_in[6];
    float* out = (float*)d_out;

    char* ws = (char*)d_ws;
    unsigned short* w1t  = (unsigned short*)(ws);                       // 67108864 B
    unsigned short* w2t  = (unsigned short*)(ws + 67108864);            // 67108864 B
    unsigned short* xpad = (unsigned short*)(ws + 134217728);           // 16779264 B
    unsigned short* hbuf = (unsigned short*)(ws + 150996992);           // 83886080 B
    int2*   tops = (int2*)  (ws + 234883072);                           // 65536 B
    float2* wtsp = (float2*)(ws + 234948608);                           // 65536 B
    int*    idxl = (int*)   (ws + 235014144);                           // 40960 B
    float*  tokw = (float*) (ws + 235055104);                           // 40960 B

    hipMemsetAsync(d_out, 0, (size_t)out_size * sizeof(float), stream);

    gate_kernel<<<S_TOK / 4, 256, 0, stream>>>(x, gw, gb, tops, wtsp);
    route_scan<<<1, 512, 0, stream>>>(tops, wtsp, idxl, tokw);
    cvt_x_kernel<<<(S_TOK * DM / 8) / 256 + 1, 256, 0, stream>>>(x, xpad);
    transpose_cvt<<<dim3(FFD / 64, DM / 64, NE), 256, 0, stream>>>(w1, w1t, DM, FFD);
    transpose_cvt<<<dim3(DM / 64, FFD / 64, NE), 256, 0, stream>>>(w2, w2t, FFD, DM);

    moe_gemm1<<<NE * (CAP / 128) * (FFD / 128), 256, 0, stream>>>(xpad, w1t, b1, idxl, hbuf);
    moe_gemm2<<<NE * (CAP / 128) * (DM / 128), 256, 0, stream>>>(hbuf, w2t, b2, idxl, tokw, out);
}

// Round 3
// 750.405 us; speedup vs baseline: 1.0426x; 1.0426x over previous
//
#include <hip/hip_runtime.h>
#include <hip/hip_bf16.h>
#include <stdint.h>

#define S_TOK 8192
#define DM    1024
#define FFD   4096
#define NE    8
#define CAP   1280

typedef __attribute__((ext_vector_type(8))) __bf16 bf16x8;
typedef __attribute__((ext_vector_type(8))) unsigned short u16x8;
typedef __attribute__((ext_vector_type(4))) float f32x4;

__device__ __forceinline__ unsigned short f2bf(float f) {
    unsigned u = __float_as_uint(f);
    unsigned r = (u + 0x7FFFu + ((u >> 16) & 1u)) >> 16;   // RNE, inputs finite
    return (unsigned short)r;
}

__device__ __forceinline__ void gload_lds16(const void* g, void* l) {
    __builtin_amdgcn_global_load_lds(
        (const __attribute__((address_space(1))) void*)g,
        (__attribute__((address_space(3))) void*)l, 16, 0, 0);
}

// ---------------- gating: one wave per token ----------------
__global__ __launch_bounds__(256) void gate_kernel(
    const float* __restrict__ x, const float* __restrict__ gw,
    const float* __restrict__ gb, int2* __restrict__ tops, float2* __restrict__ wts)
{
    int wave = threadIdx.x >> 6, lane = threadIdx.x & 63;
    int t = blockIdx.x * 4 + wave;
    float acc[NE] = {0,0,0,0,0,0,0,0};
    const float* xr = x + (size_t)t * DM;
    for (int it = 0; it < DM / 64; ++it) {
        int d = it * 64 + lane;
        float xv = xr[d];
        const float4* g4 = (const float4*)(gw + (size_t)d * NE);
        float4 a = g4[0], b = g4[1];
        acc[0] += xv * a.x; acc[1] += xv * a.y; acc[2] += xv * a.z; acc[3] += xv * a.w;
        acc[4] += xv * b.x; acc[5] += xv * b.y; acc[6] += xv * b.z; acc[7] += xv * b.w;
    }
#pragma unroll
    for (int e = 0; e < NE; ++e)
#pragma unroll
        for (int off = 32; off > 0; off >>= 1)
            acc[e] += __shfl_down(acc[e], off, 64);
    if (lane == 0) {
        float lg[NE];
#pragma unroll
        for (int e = 0; e < NE; ++e) lg[e] = acc[e] + gb[e];
        int e1 = 0; float m1 = lg[0];
#pragma unroll
        for (int e = 1; e < NE; ++e) if (lg[e] > m1) { m1 = lg[e]; e1 = e; }
        int e2 = -1; float m2 = -1e30f;
#pragma unroll
        for (int e = 0; e < NE; ++e) if (e != e1 && lg[e] > m2) { m2 = lg[e]; e2 = e; }
        float p1 = 1.f / (1.f + expf(m2 - m1));
        tops[t] = make_int2(e1, e2);
        wts[t] = make_float2(p1, 1.f - p1);
    }
}

// ---------------- capacity scan: 1 block, wave e scans all tokens ----------------
__global__ __launch_bounds__(512) void route_scan(
    const int2* __restrict__ tops, const float2* __restrict__ wts,
    int* __restrict__ idxl, float* __restrict__ tokw)
{
    int e = threadIdx.x >> 6, lane = threadIdx.x & 63;
    for (int s = lane; s < CAP; s += 64) { idxl[e * CAP + s] = S_TOK; tokw[e * CAP + s] = 0.f; }
    int base = 0;
    for (int ch = 0; ch < S_TOK / 64; ++ch) {
        int t = ch * 64 + lane;
        int2 te = tops[t];
        float2 wv = wts[t];
        bool m1 = (te.x == e), m2 = (te.y == e);
        bool a = m1 || m2;
        unsigned long long bal = __ballot(a);
        int pre = __popcll(bal & ((1ull << lane) - 1ull));
        if (a) {
            int slot = base + pre;
            if (slot < CAP) { idxl[e * CAP + slot] = t; tokw[e * CAP + slot] = m1 ? wv.x : wv.y; }
        }
        base += __popcll(bal);
    }
}

// ---------------- x fp32 -> bf16 (+zero pad row S) ----------------
__global__ __launch_bounds__(256) void cvt_x_kernel(const float* __restrict__ x,
                                                    unsigned short* __restrict__ xp)
{
    if (blockIdx.x == (S_TOK * DM / 8) / 256) {         // pad-row block
        if (threadIdx.x < DM / 8) {
            u16x8 z = {0,0,0,0,0,0,0,0};
            *(u16x8*)(xp + (size_t)S_TOK * DM + threadIdx.x * 8) = z;
        }
        return;
    }
    size_t i = (size_t)blockIdx.x * 256 + threadIdx.x;
    const float4* s = (const float4*)(x + i * 8);
    float4 a = s[0], b = s[1];
    u16x8 o;
    o[0]=f2bf(a.x); o[1]=f2bf(a.y); o[2]=f2bf(a.z); o[3]=f2bf(a.w);
    o[4]=f2bf(b.x); o[5]=f2bf(b.y); o[6]=f2bf(b.z); o[7]=f2bf(b.w);
    *(u16x8*)(xp + i * 8) = o;
}

// ---------------- (K,N) fp32 -> (N,K) bf16 transpose-convert, per expert ----------------
__global__ __launch_bounds__(256) void transpose_cvt(
    const float* __restrict__ src, unsigned short* __restrict__ dst, int K, int N)
{
    __shared__ float tile[64][65];
    size_t ebase = (size_t)blockIdx.z * K * N;
    int k0 = blockIdx.y * 64, n0 = blockIdx.x * 64;
    int t = threadIdx.x;
    int tr = t >> 4, tc = (t & 15) * 4;
#pragma unroll
    for (int rr = 0; rr < 4; ++rr) {
        int k = tr + rr * 16;
        float4 v = *(const float4*)(src + ebase + (size_t)(k0 + k) * N + n0 + tc);
        tile[tc + 0][k] = v.x; tile[tc + 1][k] = v.y; tile[tc + 2][k] = v.z; tile[tc + 3][k] = v.w;
    }
    __syncthreads();
    int nr = t >> 3, kc = (t & 7) * 8;
#pragma unroll
    for (int ww = 0; ww < 2; ++ww) {
        int n = nr + ww * 32;
        u16x8 o;
#pragma unroll
        for (int q = 0; q < 8; ++q) o[q] = f2bf(tile[n][kc + q]);
        *(u16x8*)(dst + ebase + (size_t)(n0 + n) * K + k0 + kc) = o;
    }
}

// ---------------- GEMM1: h[e] = relu(gather(x)[e] @ w1[e] + b1[e])  (bf16 out) ----------------
// grid = NE * 10 * 32; XCD-swizzled so each XCD owns one expert, tn innermost.
__global__ __launch_bounds__(256) void moe_gemm1(
    const unsigned short* __restrict__ xpad, const unsigned short* __restrict__ w1t,
    const float* __restrict__ b1, const int* __restrict__ idxl, unsigned short* __restrict__ h)
{
    __shared__ unsigned short As[128 * 64];
    __shared__ unsigned short Bs[128 * 64];
    const int MT = CAP / 128, NT = FFD / 128;                 // 10, 32
    const int NWG = NE * MT * NT;                             // 2560, %8==0
    int wgid = (blockIdx.x & 7) * (NWG / 8) + (blockIdx.x >> 3);
    int e = wgid / (MT * NT); int r = wgid % (MT * NT);
    int tm = r / NT, tn = r % NT;
    int t = threadIdx.x, wave = t >> 6, lane = t & 63;

    const unsigned short* asrc[4]; const unsigned short* bsrc[4];
#pragma unroll
    for (int i = 0; i < 4; ++i) {
        int row = (i * 256 + t) >> 3;
        int g = idxl[e * CAP + tm * 128 + row];
        asrc[i] = xpad + (size_t)g * DM + (t & 7) * 8;
        bsrc[i] = w1t + ((size_t)e * FFD + tn * 128 + row) * DM + (t & 7) * 8;
    }
    f32x4 acc[4][4] = {};
    int wr = wave >> 1, wc = wave & 1;
    int a_off = (wr * 64 + (lane & 15)) * 64 + (lane >> 4) * 8;
    int b_off = (wc * 64 + (lane & 15)) * 64 + (lane >> 4) * 8;

    for (int kt = 0; kt < DM / 64; ++kt) {
#pragma unroll
        for (int i = 0; i < 4; ++i) {
            gload_lds16(asrc[i] + kt * 64, As + (i * 4 + wave) * 512);
            gload_lds16(bsrc[i] + kt * 64, Bs + (i * 4 + wave) * 512);
        }
        __syncthreads();
#pragma unroll
        for (int kk = 0; kk < 2; ++kk) {
            bf16x8 af[4], bfr[4];
#pragma unroll
            for (int m = 0; m < 4; ++m) af[m]  = *(const bf16x8*)(As + a_off + m * 1024 + kk * 32);
#pragma unroll
            for (int n = 0; n < 4; ++n) bfr[n] = *(const bf16x8*)(Bs + b_off + n * 1024 + kk * 32);
#pragma unroll
            for (int m = 0; m < 4; ++m)
#pragma unroll
                for (int n = 0; n < 4; ++n)
                    acc[m][n] = __builtin_amdgcn_mfma_f32_16x16x32_bf16(af[m], bfr[n], acc[m][n], 0, 0, 0);
        }
        __syncthreads();
    }
    int col0 = tn * 128 + wc * 64 + (lane & 15);
    int row0 = tm * 128 + wr * 64 + ((lane >> 4) * 4);
    float bv[4];
#pragma unroll
    for (int n = 0; n < 4; ++n) bv[n] = b1[(size_t)e * FFD + col0 + n * 16];
#pragma unroll
    for (int m = 0; m < 4; ++m)
#pragma unroll
        for (int j = 0; j < 4; ++j) {
            int row = row0 + m * 16 + j;
            size_t hb = ((size_t)e * CAP + row) * FFD;
#pragma unroll
            for (int n = 0; n < 4; ++n) {
                float v = acc[m][n][j] + bv[n];
                v = fmaxf(v, 0.f);
                h[hb + col0 + n * 16] = f2bf(v);
            }
        }
}

// ---------------- GEMM2: out += scatter( (h[e] @ w2[e] + b2[e]) * tokw ) ----------------
// K-split x2 -> 1280 blocks (5/CU); XCD-swizzled: each XCD owns one (expert, K-half).
#define KSPLIT 2
#define KHALF  (FFD / KSPLIT)
__global__ __launch_bounds__(256) void moe_gemm2(
    const unsigned short* __restrict__ h, const unsigned short* __restrict__ w2t,
    const float* __restrict__ b2, const int* __restrict__ idxl, const float* __restrict__ tokw,
    float* __restrict__ out)
{
    __shared__ unsigned short As[128 * 64];
    __shared__ unsigned short Bs[128 * 64];
    const int MT = CAP / 128, NT = DM / 128;                  // 10, 8
    const int NWG = NE * KSPLIT * MT * NT;                    // 1280, %8==0
    int wgid = (blockIdx.x & 7) * (NWG / 8) + (blockIdx.x >> 3);
    int e = wgid / (KSPLIT * MT * NT); int r = wgid % (KSPLIT * MT * NT);
    int kz = r / (MT * NT); int r2 = r % (MT * NT);
    int tm = r2 / NT, tn = r2 % NT;
    int t = threadIdx.x, wave = t >> 6, lane = t & 63;

    const unsigned short* asrc[4]; const unsigned short* bsrc[4];
#pragma unroll
    for (int i = 0; i < 4; ++i) {
        int row = (i * 256 + t) >> 3;
        asrc[i] = h   + ((size_t)e * CAP + tm * 128 + row) * FFD + kz * KHALF + (t & 7) * 8;
        bsrc[i] = w2t + ((size_t)e * DM  + tn * 128 + row) * FFD + kz * KHALF + (t & 7) * 8;
    }
    f32x4 acc[4][4] = {};
    int wr = wave >> 1, wc = wave & 1;
    int a_off = (wr * 64 + (lane & 15)) * 64 + (lane >> 4) * 8;
    int b_off = (wc * 64 + (lane & 15)) * 64 + (lane >> 4) * 8;

    for (int kt = 0; kt < KHALF / 64; ++kt) {
#pragma unroll
        for (int i = 0; i < 4; ++i) {
            gload_lds16(asrc[i] + kt * 64, As + (i * 4 + wave) * 512);
            gload_lds16(bsrc[i] + kt * 64, Bs + (i * 4 + wave) * 512);
        }
        __syncthreads();
#pragma unroll
        for (int kk = 0; kk < 2; ++kk) {
            bf16x8 af[4], bfr[4];
#pragma unroll
            for (int m = 0; m < 4; ++m) af[m]  = *(const bf16x8*)(As + a_off + m * 1024 + kk * 32);
#pragma unroll
            for (int n = 0; n < 4; ++n) bfr[n] = *(const bf16x8*)(Bs + b_off + n * 1024 + kk * 32);
#pragma unroll
            for (int m = 0; m < 4; ++m)
#pragma unroll
                for (int n = 0; n < 4; ++n)
                    acc[m][n] = __builtin_amdgcn_mfma_f32_16x16x32_bf16(af[m], bfr[n], acc[m][n], 0, 0, 0);
        }
        __syncthreads();
    }
    int col0 = tn * 128 + wc * 64 + (lane & 15);
    int row0 = tm * 128 + wr * 64 + ((lane >> 4) * 4);
    float bv[4];
#pragma unroll
    for (int n = 0; n < 4; ++n) bv[n] = (kz == 0) ? b2[(size_t)e * DM + col0 + n * 16] : 0.f;
#pragma unroll
    for (int m = 0; m < 4; ++m)
#pragma unroll
        for (int j = 0; j < 4; ++j) {
            int row = row0 + m * 16 + j;
            int tok = idxl[e * CAP + row];
            float w = tokw[e * CAP + row];
            if (w != 0.f) {
                float* orow = out + (size_t)tok * DM;
#pragma unroll
                for (int n = 0; n < 4; ++n)
                    atomicAdd(orow + col0 + n * 16, (acc[m][n][j] + bv[n]) * w);
            }
        }
}

extern "C" void kernel_launch(void* const* d_in, const int* in_sizes, int n_in,
                              void* d_out, int out_size, void* d_ws, size_t ws_size,
                              hipStream_t stream) {
    (void)in_sizes; (void)n_in; (void)ws_size;
    const float* x  = (const float*)d_in[0];
    const float* gw = (const float*)d_in[1];
    const float* gb = (const float*)d_in[2];
    const float* w1 = (const float*)d_in[3];
    const float* b1 = (const float*)d_in[4];
    const float* w2 = (const float*)d_in[5];
    const float* b2 = (const float*)d_in[6];
    float* out = (float*)d_out;

    char* ws = (char*)d_ws;
    unsigned short* w1t  = (unsigned short*)(ws);                       // 67108864 B
    unsigned short* w2t  = (unsigned short*)(ws + 67108864);            // 67108864 B
    unsigned short* xpad = (unsigned short*)(ws + 134217728);           // 16779264 B
    unsigned short* hbuf = (unsigned short*)(ws + 150996992);           // 83886080 B
    int2*   tops = (int2*)  (ws + 234883072);                           // 65536 B
    float2* wtsp = (float2*)(ws + 234948608);                           // 65536 B
    int*    idxl = (int*)   (ws + 235014144);                           // 40960 B
    float*  tokw = (float*) (ws + 235055104);                           // 40960 B

    hipMemsetAsync(d_out, 0, (size_t)out_size * sizeof(float), stream);

    gate_kernel<<<S_TOK / 4, 256, 0, stream>>>(x, gw, gb, tops, wtsp);
    route_scan<<<1, 512, 0, stream>>>(tops, wtsp, idxl, tokw);
    cvt_x_kernel<<<(S_TOK * DM / 8) / 256 + 1, 256, 0, stream>>>(x, xpad);
    transpose_cvt<<<dim3(FFD / 64, DM / 64, NE), 256, 0, stream>>>(w1, w1t, DM, FFD);
    transpose_cvt<<<dim3(DM / 64, FFD / 64, NE), 256, 0, stream>>>(w2, w2t, FFD, DM);

    moe_gemm1<<<NE * (CAP / 128) * (FFD / 128), 256, 0, stream>>>(xpad, w1t, b1, idxl, hbuf);
    moe_gemm2<<<NE * KSPLIT * (CAP / 128) * (DM / 128), 256, 0, stream>>>(hbuf, w2t, b2, idxl, tokw, out);
}

// Round 5
// 696.110 us; speedup vs baseline: 1.1239x; 1.0780x over previous
//
#include <hip/hip_runtime.h>
#include <hip/hip_bf16.h>
#include <stdint.h>

#define S_TOK 8192
#define DM    1024
#define FFD   4096
#define NE    8
#define CAP   1280
#define NCH   16          // routing chunks (512 tokens each)

typedef __attribute__((ext_vector_type(8))) __bf16 bf16x8;
typedef __attribute__((ext_vector_type(8))) unsigned short u16x8;
typedef __attribute__((ext_vector_type(4))) float f32x4;

__device__ __forceinline__ unsigned short f2bf(float f) {
    unsigned u = __float_as_uint(f);
    unsigned r = (u + 0x7FFFu + ((u >> 16) & 1u)) >> 16;   // RNE, inputs finite
    return (unsigned short)r;
}

__device__ __forceinline__ void gload_lds16(const void* g, void* l) {
    __builtin_amdgcn_global_load_lds(
        (const __attribute__((address_space(1))) void*)g,
        (__attribute__((address_space(3))) void*)l, 16, 0, 0);
}

// ---------------- gating: one wave per token ----------------
__global__ __launch_bounds__(256) void gate_kernel(
    const float* __restrict__ x, const float* __restrict__ gw,
    const float* __restrict__ gb, int2* __restrict__ tops, float2* __restrict__ wts)
{
    int wave = threadIdx.x >> 6, lane = threadIdx.x & 63;
    int t = blockIdx.x * 4 + wave;
    float acc[NE] = {0,0,0,0,0,0,0,0};
    const float* xr = x + (size_t)t * DM;
    for (int it = 0; it < DM / 64; ++it) {
        int d = it * 64 + lane;
        float xv = xr[d];
        const float4* g4 = (const float4*)(gw + (size_t)d * NE);
        float4 a = g4[0], b = g4[1];
        acc[0] += xv * a.x; acc[1] += xv * a.y; acc[2] += xv * a.z; acc[3] += xv * a.w;
        acc[4] += xv * b.x; acc[5] += xv * b.y; acc[6] += xv * b.z; acc[7] += xv * b.w;
    }
#pragma unroll
    for (int e = 0; e < NE; ++e)
#pragma unroll
        for (int off = 32; off > 0; off >>= 1)
            acc[e] += __shfl_down(acc[e], off, 64);
    if (lane == 0) {
        float lg[NE];
#pragma unroll
        for (int e = 0; e < NE; ++e) lg[e] = acc[e] + gb[e];
        int e1 = 0; float m1 = lg[0];
#pragma unroll
        for (int e = 1; e < NE; ++e) if (lg[e] > m1) { m1 = lg[e]; e1 = e; }
        int e2 = -1; float m2 = -1e30f;
#pragma unroll
        for (int e = 0; e < NE; ++e) if (e != e1 && lg[e] > m2) { m2 = lg[e]; e2 = e; }
        float p1 = 1.f / (1.f + expf(m2 - m1));
        tops[t] = make_int2(e1, e2);
        wts[t] = make_float2(p1, 1.f - p1);
    }
}

// ---------------- routing, parallel: hist -> offset -> scatter ----------------
__global__ __launch_bounds__(512) void route_hist(
    const int2* __restrict__ tops, int* __restrict__ cnt,
    int* __restrict__ idxl, float* __restrict__ tokw)
{
    int e = threadIdx.x >> 6, lane = threadIdx.x & 63;
    int c = blockIdx.x;
    for (int i = blockIdx.x * 512 + threadIdx.x; i < NE * CAP; i += NCH * 512) {
        idxl[i] = S_TOK; tokw[i] = 0.f;
    }
    int n = 0;
#pragma unroll
    for (int sub = 0; sub < 8; ++sub) {
        int t = c * 512 + sub * 64 + lane;
        int2 te = tops[t];
        bool a = (te.x == e) || (te.y == e);
        n += __popcll(__ballot(a));
    }
    if (lane == 0) cnt[c * NE + e] = n;
}

__global__ void route_offset(const int* __restrict__ cnt, int* __restrict__ baseArr)
{
    int e = threadIdx.x;
    if (e < NE) {
        int run = 0;
        for (int c = 0; c < NCH; ++c) { baseArr[c * NE + e] = run; run += cnt[c * NE + e]; }
    }
}

__global__ __launch_bounds__(512) void route_scatter(
    const int2* __restrict__ tops, const float2* __restrict__ wts,
    const int* __restrict__ baseArr, int* __restrict__ idxl, float* __restrict__ tokw)
{
    int e = threadIdx.x >> 6, lane = threadIdx.x & 63;
    int c = blockIdx.x;
    int base = baseArr[c * NE + e];
#pragma unroll
    for (int sub = 0; sub < 8; ++sub) {
        int t = c * 512 + sub * 64 + lane;
        int2 te = tops[t];
        float2 wv = wts[t];
        bool m1 = (te.x == e);
        bool a = m1 || (te.y == e);
        unsigned long long bal = __ballot(a);
        int pre = __popcll(bal & ((1ull << lane) - 1ull));
        if (a) {
            int slot = base + pre;
            if (slot < CAP) { idxl[e * CAP + slot] = t; tokw[e * CAP + slot] = m1 ? wv.x : wv.y; }
        }
        base += __popcll(bal);
    }
}

// ---------------- x fp32 -> bf16 (+zero pad row S) ----------------
__global__ __launch_bounds__(256) void cvt_x_kernel(const float* __restrict__ x,
                                                    unsigned short* __restrict__ xp)
{
    if (blockIdx.x == (S_TOK * DM / 8) / 256) {         // pad-row block
        if (threadIdx.x < DM / 8) {
            u16x8 z = {0,0,0,0,0,0,0,0};
            *(u16x8*)(xp + (size_t)S_TOK * DM + threadIdx.x * 8) = z;
        }
        return;
    }
    size_t i = (size_t)blockIdx.x * 256 + threadIdx.x;
    const float4* s = (const float4*)(x + i * 8);
    float4 a = s[0], b = s[1];
    u16x8 o;
    o[0]=f2bf(a.x); o[1]=f2bf(a.y); o[2]=f2bf(a.z); o[3]=f2bf(a.w);
    o[4]=f2bf(b.x); o[5]=f2bf(b.y); o[6]=f2bf(b.z); o[7]=f2bf(b.w);
    *(u16x8*)(xp + i * 8) = o;
}

// ---------------- (K,N) fp32 -> (N,K) bf16 transpose-convert, per expert ----------------
__global__ __launch_bounds__(256) void transpose_cvt(
    const float* __restrict__ src, unsigned short* __restrict__ dst, int K, int N)
{
    __shared__ float tile[64][65];
    size_t ebase = (size_t)blockIdx.z * K * N;
    int k0 = blockIdx.y * 64, n0 = blockIdx.x * 64;
    int t = threadIdx.x;
    int tr = t >> 4, tc = (t & 15) * 4;
#pragma unroll
    for (int rr = 0; rr < 4; ++rr) {
        int k = tr + rr * 16;
        float4 v = *(const float4*)(src + ebase + (size_t)(k0 + k) * N + n0 + tc);
        tile[tc + 0][k] = v.x; tile[tc + 1][k] = v.y; tile[tc + 2][k] = v.z; tile[tc + 3][k] = v.w;
    }
    __syncthreads();
    int nr = t >> 3, kc = (t & 7) * 8;
#pragma unroll
    for (int ww = 0; ww < 2; ++ww) {
        int n = nr + ww * 32;
        u16x8 o;
#pragma unroll
        for (int q = 0; q < 8; ++q) o[q] = f2bf(tile[n][kc + q]);
        *(u16x8*)(dst + ebase + (size_t)(n0 + n) * K + k0 + kc) = o;
    }
}

// ---------------- GEMM1: h[e] = relu(gather(x)[e] @ w1[e] + b1[e])  (bf16 out) ----------------
// XCD-swizzled (expert per XCD) + L2 super-tiles: phase = all 10 tm x 4 tn (3.5MB).
__global__ __launch_bounds__(256) void moe_gemm1(
    const unsigned short* __restrict__ xpad, const unsigned short* __restrict__ w1t,
    const float* __restrict__ b1, const int* __restrict__ idxl, unsigned short* __restrict__ h)
{
    __shared__ unsigned short As[128 * 64];
    __shared__ unsigned short Bs[128 * 64];
    const int MT = CAP / 128, NT = FFD / 128;                 // 10, 32
    const int NWG = NE * MT * NT;                             // 2560, %8==0
    int wgid = (blockIdx.x & 7) * (NWG / 8) + (blockIdx.x >> 3);
    int e = wgid / (MT * NT); int r = wgid % (MT * NT);
    int tnc = r / (MT * 4); int q = r % (MT * 4);             // 8 phases of 40 blocks
    int tm = q >> 2, tn = tnc * 4 + (q & 3);
    int t = threadIdx.x, wave = t >> 6, lane = t & 63;

    const unsigned short* asrc[4]; const unsigned short* bsrc[4];
#pragma unroll
    for (int i = 0; i < 4; ++i) {
        int row = (i * 256 + t) >> 3;
        int g = idxl[e * CAP + tm * 128 + row];
        asrc[i] = xpad + (size_t)g * DM + (t & 7) * 8;
        bsrc[i] = w1t + ((size_t)e * FFD + tn * 128 + row) * DM + (t & 7) * 8;
    }
    f32x4 acc[4][4] = {};
    int wr = wave >> 1, wc = wave & 1;
    int a_off = (wr * 64 + (lane & 15)) * 64 + (lane >> 4) * 8;
    int b_off = (wc * 64 + (lane & 15)) * 64 + (lane >> 4) * 8;

    for (int kt = 0; kt < DM / 64; ++kt) {
#pragma unroll
        for (int i = 0; i < 4; ++i) {
            gload_lds16(asrc[i] + kt * 64, As + (i * 4 + wave) * 512);
            gload_lds16(bsrc[i] + kt * 64, Bs + (i * 4 + wave) * 512);
        }
        __syncthreads();
#pragma unroll
        for (int kk = 0; kk < 2; ++kk) {
            bf16x8 af[4], bfr[4];
#pragma unroll
            for (int m = 0; m < 4; ++m) af[m]  = *(const bf16x8*)(As + a_off + m * 1024 + kk * 32);
#pragma unroll
            for (int n = 0; n < 4; ++n) bfr[n] = *(const bf16x8*)(Bs + b_off + n * 1024 + kk * 32);
#pragma unroll
            for (int m = 0; m < 4; ++m)
#pragma unroll
                for (int n = 0; n < 4; ++n)
                    acc[m][n] = __builtin_amdgcn_mfma_f32_16x16x32_bf16(af[m], bfr[n], acc[m][n], 0, 0, 0);
        }
        __syncthreads();
    }
    int col0 = tn * 128 + wc * 64 + (lane & 15);
    int row0 = tm * 128 + wr * 64 + ((lane >> 4) * 4);
    float bv[4];
#pragma unroll
    for (int n = 0; n < 4; ++n) bv[n] = b1[(size_t)e * FFD + col0 + n * 16];
#pragma unroll
    for (int m = 0; m < 4; ++m)
#pragma unroll
        for (int j = 0; j < 4; ++j) {
            int row = row0 + m * 16 + j;
            size_t hb = ((size_t)e * CAP + row) * FFD;
#pragma unroll
            for (int n = 0; n < 4; ++n) {
                float v = acc[m][n][j] + bv[n];
                v = fmaxf(v, 0.f);
                h[hb + col0 + n * 16] = f2bf(v);
            }
        }
}

// ---------------- GEMM2: out += scatter( (h[e] @ w2[e] + b2[e]) * tokw ) ----------------
// K-split x2; XCD owns one expert; super-tiles of (5 tm x 4 tn) ~4.5MB.
#define KSPLIT 2
#define KHALF  (FFD / KSPLIT)
__global__ __launch_bounds__(256) void moe_gemm2(
    const unsigned short* __restrict__ h, const unsigned short* __restrict__ w2t,
    const float* __restrict__ b2, const int* __restrict__ idxl, const float* __restrict__ tokw,
    float* __restrict__ out)
{
    __shared__ unsigned short As[128 * 64];
    __shared__ unsigned short Bs[128 * 64];
    const int MT = CAP / 128, NT = DM / 128;                  // 10, 8
    const int NWG = NE * KSPLIT * MT * NT;                    // 1280, %8==0
    int wgid = (blockIdx.x & 7) * (NWG / 8) + (blockIdx.x >> 3);
    int e = wgid / (KSPLIT * MT * NT); int r = wgid % (KSPLIT * MT * NT);
    int kz = r / (MT * NT); int r2 = r % (MT * NT);
    int p = r2 / 20; int q = r2 % 20;                         // 4 phases of 20 blocks
    int tm = (p >> 1) * 5 + (q >> 2);
    int tn = (p & 1) * 4 + (q & 3);
    int t = threadIdx.x, wave = t >> 6, lane = t & 63;

    const unsigned short* asrc[4]; const unsigned short* bsrc[4];
#pragma unroll
    for (int i = 0; i < 4; ++i) {
        int row = (i * 256 + t) >> 3;
        asrc[i] = h   + ((size_t)e * CAP + tm * 128 + row) * FFD + kz * KHALF + (t & 7) * 8;
        bsrc[i] = w2t + ((size_t)e * DM  + tn * 128 + row) * FFD + kz * KHALF + (t & 7) * 8;
    }
    f32x4 acc[4][4] = {};
    int wr = wave >> 1, wc = wave & 1;
    int a_off = (wr * 64 + (lane & 15)) * 64 + (lane >> 4) * 8;
    int b_off = (wc * 64 + (lane & 15)) * 64 + (lane >> 4) * 8;

    for (int kt = 0; kt < KHALF / 64; ++kt) {
#pragma unroll
        for (int i = 0; i < 4; ++i) {
            gload_lds16(asrc[i] + kt * 64, As + (i * 4 + wave) * 512);
            gload_lds16(bsrc[i] + kt * 64, Bs + (i * 4 + wave) * 512);
        }
        __syncthreads();
#pragma unroll
        for (int kk = 0; kk < 2; ++kk) {
            bf16x8 af[4], bfr[4];
#pragma unroll
            for (int m = 0; m < 4; ++m) af[m]  = *(const bf16x8*)(As + a_off + m * 1024 + kk * 32);
#pragma unroll
            for (int n = 0; n < 4; ++n) bfr[n] = *(const bf16x8*)(Bs + b_off + n * 1024 + kk * 32);
#pragma unroll
            for (int m = 0; m < 4; ++m)
#pragma unroll
                for (int n = 0; n < 4; ++n)
                    acc[m][n] = __builtin_amdgcn_mfma_f32_16x16x32_bf16(af[m], bfr[n], acc[m][n], 0, 0, 0);
        }
        __syncthreads();
    }
    int col0 = tn * 128 + wc * 64 + (lane & 15);
    int row0 = tm * 128 + wr * 64 + ((lane >> 4) * 4);
    float bv[4];
#pragma unroll
    for (int n = 0; n < 4; ++n) bv[n] = (kz == 0) ? b2[(size_t)e * DM + col0 + n * 16] : 0.f;
#pragma unroll
    for (int m = 0; m < 4; ++m)
#pragma unroll
        for (int j = 0; j < 4; ++j) {
            int row = row0 + m * 16 + j;
            int tok = idxl[e * CAP + row];
            float w = tokw[e * CAP + row];
            if (w != 0.f) {
                float* orow = out + (size_t)tok * DM;
#pragma unroll
                for (int n = 0; n < 4; ++n)
                    atomicAdd(orow + col0 + n * 16, (acc[m][n][j] + bv[n]) * w);
            }
        }
}

extern "C" void kernel_launch(void* const* d_in, const int* in_sizes, int n_in,
                              void* d_out, int out_size, void* d_ws, size_t ws_size,
                              hipStream_t stream) {
    (void)in_sizes; (void)n_in; (void)ws_size;
    const float* x  = (const float*)d_in[0];
    const float* gw = (const float*)d_in[1];
    const float* gb = (const float*)d_in[2];
    const float* w1 = (const float*)d_in[3];
    const float* b1 = (const float*)d_in[4];
    const float* w2 = (const float*)d_in[5];
    const float* b2 = (const float*)d_in[6];
    float* out = (float*)d_out;

    char* ws = (char*)d_ws;
    unsigned short* w1t  = (unsigned short*)(ws);                       // 67108864 B
    unsigned short* w2t  = (unsigned short*)(ws + 67108864);            // 67108864 B
    unsigned short* xpad = (unsigned short*)(ws + 134217728);           // 16779264 B
    unsigned short* hbuf = (unsigned short*)(ws + 150996992);           // 83886080 B
    int2*   tops = (int2*)  (ws + 234883072);                           // 65536 B
    float2* wtsp = (float2*)(ws + 234948608);                           // 65536 B
    int*    idxl = (int*)   (ws + 235014144);                           // 40960 B
    float*  tokw = (float*) (ws + 235055104);                           // 40960 B
    int*    cnt  = (int*)   (ws + 235096064);                           // 512 B
    int*    bas  = (int*)   (ws + 235096576);                           // 512 B

    hipMemsetAsync(d_out, 0, (size_t)out_size * sizeof(float), stream);

    gate_kernel<<<S_TOK / 4, 256, 0, stream>>>(x, gw, gb, tops, wtsp);
    route_hist<<<NCH, 512, 0, stream>>>(tops, cnt, idxl, tokw);
    route_offset<<<1, 64, 0, stream>>>(cnt, bas);
    route_scatter<<<NCH, 512, 0, stream>>>(tops, wtsp, bas, idxl, tokw);
    cvt_x_kernel<<<(S_TOK * DM / 8) / 256 + 1, 256, 0, stream>>>(x, xpad);
    transpose_cvt<<<dim3(FFD / 64, DM / 64, NE), 256, 0, stream>>>(w1, w1t, DM, FFD);
    transpose_cvt<<<dim3(DM / 64, FFD / 64, NE), 256, 0, stream>>>(w2, w2t, FFD, DM);

    moe_gemm1<<<NE * (CAP / 128) * (FFD / 128), 256, 0, stream>>>(xpad, w1t, b1, idxl, hbuf);
    moe_gemm2<<<NE * KSPLIT * (CAP / 128) * (DM / 128), 256, 0, stream>>>(hbuf, w2t, b2, idxl, tokw, out);
}